// Round 4
// baseline (583.817 us; speedup 1.0000x reference)
//
#include <hip/hip_runtime.h>

// ---------------------------------------------------------------------------
// GIN encoder, fp16 feature path + MFMA, quartered L2-resident aggregation.
// h is stored as 4 column-quarter planes (3.2 MB each < 4 MB per-XCD L2).
// Per layer: 4x agg pass (one plane each, fused BN of prev layer)
//            -> fused MLP kernel (gemm1+ReLU -> LDS transpose -> gemm2+ReLU
//               + column stats) -> finalize (computes scale/shift, re-zeros).
// BN apply folded into next aggregate: BN(h) summed over {self + deg nbrs}
// = scale*(raw agg) + (1+deg)*shift. Last layer's BN folds into pooling.
// ---------------------------------------------------------------------------

typedef __attribute__((ext_vector_type(8))) _Float16 f16x8;
typedef __attribute__((ext_vector_type(4))) float f32x4;

static __device__ __forceinline__ float h2f(unsigned short u) {
  return (float)__builtin_bit_cast(_Float16, u);
}
static __device__ __forceinline__ unsigned short f2h(float f) {
  return __builtin_bit_cast(unsigned short, (_Float16)f);
}
static __device__ __forceinline__ float lo16(unsigned int v) { return h2f((unsigned short)(v & 0xffffu)); }
static __device__ __forceinline__ float hi16(unsigned int v) { return h2f((unsigned short)(v >> 16)); }

// ---- CSR build ----
__global__ __launch_bounds__(256) void hist_kernel(const int* __restrict__ dst,
                                                   int* __restrict__ counts, int E) {
  int e = blockIdx.x * 256 + threadIdx.x;
  if (e < E) atomicAdd(&counts[dst[e]], 1);
}

__global__ __launch_bounds__(512) void scan1_kernel(const int* __restrict__ counts,
                                                    int* __restrict__ incl,
                                                    int* __restrict__ bsums, int n) {
  __shared__ int buf[2][512];
  int t = threadIdx.x;
  int i = blockIdx.x * 512 + t;
  buf[0][t] = (i < n) ? counts[i] : 0;
  __syncthreads();
  int cur = 0;
  for (int off = 1; off < 512; off <<= 1) {
    buf[cur ^ 1][t] = buf[cur][t] + ((t >= off) ? buf[cur][t - off] : 0);
    __syncthreads();
    cur ^= 1;
  }
  if (i < n) incl[i] = buf[cur][t];
  if (t == 511) bsums[blockIdx.x] = buf[cur][511];
}

__global__ __launch_bounds__(128) void scan2_kernel(int* __restrict__ bsums, int nb) {
  __shared__ int buf[2][128];
  int t = threadIdx.x;
  int v = (t < nb) ? bsums[t] : 0;
  buf[0][t] = v;
  __syncthreads();
  int cur = 0;
  for (int off = 1; off < 128; off <<= 1) {
    buf[cur ^ 1][t] = buf[cur][t] + ((t >= off) ? buf[cur][t - off] : 0);
    __syncthreads();
    cur ^= 1;
  }
  if (t < nb) bsums[t] = buf[cur][t] - v;  // exclusive
}

__global__ __launch_bounds__(256) void scan3_kernel(const int* __restrict__ counts,
                                                    const int* __restrict__ incl,
                                                    const int* __restrict__ bsums,
                                                    int* __restrict__ offsets,
                                                    int* __restrict__ cursor, int n) {
  int i = blockIdx.x * 256 + threadIdx.x;
  if (i < n) {
    int total = bsums[i >> 9] + incl[i];
    offsets[i + 1] = total;
    cursor[i] = total - counts[i];
  }
  if (i == 0) offsets[0] = 0;
}

__global__ __launch_bounds__(256) void fill_kernel(const int* __restrict__ src,
                                                   const int* __restrict__ dst,
                                                   int* cursor, int* __restrict__ srcs, int E) {
  int e = blockIdx.x * 256 + threadIdx.x;
  if (e < E) {
    int p = atomicAdd(&cursor[dst[e]], 1);
    srcs[p] = src[e];
  }
}

// ---- prep: x -> fp16 quarter planes; zero counts; init affine + stats ----
__global__ __launch_bounds__(256) void prep_kernel(const float* __restrict__ x,
                                                   unsigned int* __restrict__ hplanes,
                                                   int* __restrict__ counts,
                                                   float* __restrict__ scale,
                                                   float* __restrict__ shift,
                                                   float* __restrict__ sums,
                                                   float* __restrict__ sumsq, int M) {
  int stride = gridDim.x * 256;
  int tid = blockIdx.x * 256 + threadIdx.x;
  const float2* x2 = (const float2*)x;
  int total = M * 64;
  for (int i = tid; i < total; i += stride) {
    int n = i >> 6, rem = i & 63, q = rem >> 4, j = rem & 15;
    float2 v = x2[n * 64 + q * 16 + j];
    hplanes[(size_t)q * M * 16 + n * 16 + j] =
        (unsigned int)f2h(v.x) | ((unsigned int)f2h(v.y) << 16);
  }
  for (int i = tid; i < M; i += stride) counts[i] = 0;
  if (tid < 128) { scale[tid] = 1.f; shift[tid] = 0.f; sums[tid] = 0.f; sumsq[tid] = 0.f; }
}

// WT[m][n][k] = f16(W_m[k][n]), m in [0, 2L): even=W1 layer m/2, odd=W2 layer m/2
__global__ __launch_bounds__(256) void prep_w_kernel(const float* __restrict__ W1,
                                                     const float* __restrict__ W2,
                                                     unsigned short* __restrict__ WT, int total) {
  int idx = blockIdx.x * 256 + threadIdx.x;
  if (idx >= total) return;
  int m = idx >> 14;
  int rem = idx & 16383;
  int n = rem >> 7, k = rem & 127;
  const float* W = ((m & 1) == 0) ? (W1 + (size_t)(m >> 1) * 16384)
                                  : (W2 + (size_t)(m >> 1) * 16384);
  WT[idx] = f2h(W[k * 128 + n]);
}

// ---- aggregate one quarter-plane (L2-resident), fused BN of prev layer ----
// 16 lanes per node; agg row-major output.
__global__ __launch_bounds__(256) void agg_kernel(const unsigned int* __restrict__ plane,
                                                  const int* __restrict__ offsets,
                                                  const int* __restrict__ srcs,
                                                  const float* __restrict__ scale,
                                                  const float* __restrict__ shift,
                                                  unsigned int* __restrict__ agg,
                                                  int M, int qoff) {
  int idx = blockIdx.x * 256 + threadIdx.x;
  int node = idx >> 4, l = idx & 15;
  if (node >= M) return;
  unsigned int self = plane[node * 16 + l];
  float ax = lo16(self), ay = hi16(self);
  int e0 = offsets[node], e1 = offsets[node + 1];
  int e = e0;
  for (; e + 4 <= e1; e += 4) {
    int s0 = srcs[e], s1 = srcs[e + 1], s2 = srcs[e + 2], s3 = srcs[e + 3];
    unsigned int v0 = plane[s0 * 16 + l];
    unsigned int v1 = plane[s1 * 16 + l];
    unsigned int v2 = plane[s2 * 16 + l];
    unsigned int v3 = plane[s3 * 16 + l];
    ax += lo16(v0) + lo16(v1) + lo16(v2) + lo16(v3);
    ay += hi16(v0) + hi16(v1) + hi16(v2) + hi16(v3);
  }
  for (; e < e1; ++e) {
    unsigned int v = plane[srcs[e] * 16 + l];
    ax += lo16(v);
    ay += hi16(v);
  }
  float deg1 = (float)(e1 - e0 + 1);
  float ox = ax * scale[2 * l] + deg1 * shift[2 * l];
  float oy = ay * scale[2 * l + 1] + deg1 * shift[2 * l + 1];
  agg[(size_t)node * 64 + qoff + l] = (unsigned int)f2h(ox) | ((unsigned int)f2h(oy) << 16);
}

// ---- fused MLP: H = ReLU(ReLU(A@W1+b1)@W2+b2), + column stats.
// Block = 4 waves x 16 rows. Intermediate 64x128 fp16 tile in LDS,
// XOR-swizzled (byte ^ ((row&7)<<4)) to kill the 256B-stride bank conflict.
// A-frag: lane holds A[row0+(l&15)][ks*32+(l>>4)*8 ..+8]; B from WT (=W^T).
// C/D: col = lane&15, row = (lane>>4)*4 + reg  [m89, dtype-independent]
__global__ __launch_bounds__(256) void mlp_kernel(const unsigned short* __restrict__ A,
                                                  const unsigned short* __restrict__ WT1,
                                                  const float* __restrict__ b1,
                                                  const unsigned short* __restrict__ WT2,
                                                  const float* __restrict__ b2,
                                                  unsigned int* __restrict__ Hplanes,
                                                  float* __restrict__ sums,
                                                  float* __restrict__ sumsq, int M) {
  __shared__ unsigned short sT[64 * 128];
  __shared__ float s_sum[128], s_sq[128];
  int t = threadIdx.x;
  if (t < 128) { s_sum[t] = 0.f; s_sq[t] = 0.f; }
  int wave = t >> 6, lane = t & 63;
  int lrow = lane & 15, hi = lane >> 4;
  int lk = hi * 8;
  int row0 = (blockIdx.x * 4 + wave) * 16;

  // GEMM1
  int arow = min(row0 + lrow, M - 1);
  const unsigned short* Ap = A + (size_t)arow * 128 + lk;
  f16x8 a[4];
#pragma unroll
  for (int ks = 0; ks < 4; ++ks) a[ks] = *(const f16x8*)(Ap + ks * 32);
  f32x4 acc[8];
#pragma unroll
  for (int n = 0; n < 8; ++n) acc[n] = (f32x4){0.f, 0.f, 0.f, 0.f};
#pragma unroll
  for (int ks = 0; ks < 4; ++ks) {
    f16x8 bf[8];
#pragma unroll
    for (int n = 0; n < 8; ++n)
      bf[n] = *(const f16x8*)(WT1 + (size_t)(n * 16 + lrow) * 128 + ks * 32 + lk);
#pragma unroll
    for (int n = 0; n < 8; ++n)
      acc[n] = __builtin_amdgcn_mfma_f32_16x16x32_f16(a[ks], bf[n], acc[n], 0, 0, 0);
  }
  // epilogue1 -> swizzled LDS tile
  char* sTb = (char*)sT;
#pragma unroll
  for (int n = 0; n < 8; ++n) {
    int col = n * 16 + lrow;
    float bia = b1[col];
#pragma unroll
    for (int r = 0; r < 4; ++r) {
      int rl = wave * 16 + hi * 4 + r;
      float v = fmaxf(acc[n][r] + bia, 0.f);
      *(unsigned short*)(sTb + rl * 256 + ((col * 2) ^ ((rl & 7) << 4))) = f2h(v);
    }
  }
  __syncthreads();

  // GEMM2
  int rl2 = wave * 16 + lrow;
  f16x8 a2[4];
#pragma unroll
  for (int ks = 0; ks < 4; ++ks)
    a2[ks] = *(const f16x8*)(sTb + rl2 * 256 + ((ks * 64 + hi * 16) ^ ((rl2 & 7) << 4)));
#pragma unroll
  for (int n = 0; n < 8; ++n) acc[n] = (f32x4){0.f, 0.f, 0.f, 0.f};
#pragma unroll
  for (int ks = 0; ks < 4; ++ks) {
    f16x8 bf[8];
#pragma unroll
    for (int n = 0; n < 8; ++n)
      bf[n] = *(const f16x8*)(WT2 + (size_t)(n * 16 + lrow) * 128 + ks * 32 + lk);
#pragma unroll
    for (int n = 0; n < 8; ++n)
      acc[n] = __builtin_amdgcn_mfma_f32_16x16x32_f16(a2[ks], bf[n], acc[n], 0, 0, 0);
  }

  // epilogue2: ReLU + plane writes + column stats
  int rbase = row0 + hi * 4;
#pragma unroll
  for (int n = 0; n < 8; ++n) {
    int col = n * 16 + lrow;
    float bia = b2[col];
    int q = col >> 5;
    int jj = (col & 31) >> 1;
    float cs = 0.f, cq = 0.f;
#pragma unroll
    for (int r = 0; r < 4; ++r) {
      int rr = rbase + r;
      float v = fmaxf(acc[n][r] + bia, 0.f);
      if (rr < M) {
        unsigned short* p = (unsigned short*)(Hplanes + (size_t)q * M * 16 + rr * 16 + jj);
        p[col & 1] = f2h(v);
        cs += v;
        cq += v * v;
      }
    }
    cs += __shfl_xor(cs, 16); cs += __shfl_xor(cs, 32);
    cq += __shfl_xor(cq, 16); cq += __shfl_xor(cq, 32);
    if (hi == 0) {
      atomicAdd(&s_sum[col], cs);
      atomicAdd(&s_sq[col], cq);
    }
  }
  __syncthreads();
  if (t < 128) {
    atomicAdd(&sums[t], s_sum[t]);
    atomicAdd(&sumsq[t], s_sq[t]);
  }
}

// computes scale/shift and re-zeros the accumulators for the next layer
__global__ void bn_finalize_kernel(float* __restrict__ sums, float* __restrict__ sumsq,
                                   const float* __restrict__ gamma, const float* __restrict__ beta,
                                   float* __restrict__ scale, float* __restrict__ shift,
                                   float invM) {
  int c = threadIdx.x;
  float mean = sums[c] * invM;
  float var = fmaxf(sumsq[c] * invM - mean * mean, 0.f);
  float sc = gamma[c] * rsqrtf(var + 1e-5f);
  scale[c] = sc;
  shift[c] = beta[c] - mean * sc;
  sums[c] = 0.f;
  sumsq[c] = 0.f;
}

// ---- fused pool (BN of last layer) + projection ----
__global__ __launch_bounds__(256) void pool_proj_kernel(const unsigned int* __restrict__ H,
                                                        const int* __restrict__ batch,
                                                        const float* __restrict__ scale,
                                                        const float* __restrict__ shift,
                                                        const float* __restrict__ Wp,
                                                        const float* __restrict__ bp,
                                                        float* __restrict__ out, int M) {
  int gid = blockIdx.x;
  int lo = 0, hi = M;
  while (lo < hi) { int mid = (lo + hi) >> 1; if (batch[mid] < gid) lo = mid + 1; else hi = mid; }
  int s = lo;
  lo = 0; hi = M;
  while (lo < hi) { int mid = (lo + hi) >> 1; if (batch[mid] < gid + 1) lo = mid + 1; else hi = mid; }
  int e = lo;
  int t = threadIdx.x, c = t & 127;
  int q = c >> 5, jj = (c & 31) >> 1, half = c & 1;
  const unsigned int* plane = H + (size_t)q * M * 16;
  float acc = 0.f;
  for (int r = s + (t >> 7); r < e; r += 2) {
    unsigned int v = plane[r * 16 + jj];
    acc += half ? hi16(v) : lo16(v);
  }
  __shared__ float red[256];
  __shared__ float g[128];
  red[t] = acc;
  __syncthreads();
  if (t < 128) g[t] = (red[t] + red[t + 128]) * scale[t] + (float)(e - s) * shift[t];
  __syncthreads();
  if (t < 128) {
    float a2 = bp[t];
#pragma unroll 8
    for (int k = 0; k < 128; ++k) a2 = fmaf(g[k], Wp[k * 128 + t], a2);
    out[gid * 128 + t] = fmaxf(a2, 0.f);
  }
}

extern "C" void kernel_launch(void* const* d_in, const int* in_sizes, int n_in,
                              void* d_out, int out_size, void* d_ws, size_t ws_size,
                              hipStream_t stream) {
  const float* x = (const float*)d_in[0];
  const int* ei = (const int*)d_in[1];
  const int* batch = (const int*)d_in[2];
  const float* W1 = (const float*)d_in[3];
  const float* b1 = (const float*)d_in[4];
  const float* W2 = (const float*)d_in[5];
  const float* b2 = (const float*)d_in[6];
  const float* gamma = (const float*)d_in[7];
  const float* beta = (const float*)d_in[8];
  const float* Wp = (const float*)d_in[9];
  const float* bp = (const float*)d_in[10];
  float* out = (float*)d_out;

  int M = in_sizes[0] / 128;
  int E = in_sizes[1] / 2;
  int L = in_sizes[3] / (128 * 128);
  int G = out_size / 128;
  const int* srcp = ei;
  const int* dstp = ei + E;

  char* w = (char*)d_ws;
  auto alloc = [&](size_t bytes) {
    char* p = w;
    w += (bytes + 255) & ~(size_t)255;
    return p;
  };
  unsigned int* hbuf = (unsigned int*)alloc((size_t)M * 64 * 4);    // 4 planes of M*16 uints
  unsigned int* aggbuf = (unsigned int*)alloc((size_t)M * 64 * 4);  // row-major fp16 (uint-packed)
  unsigned short* WT = (unsigned short*)alloc((size_t)L * 2 * 16384 * 2);
  int* counts = (int*)alloc((size_t)M * 4);
  int* incl = (int*)alloc((size_t)M * 4);
  int* bsums = (int*)alloc(128 * 4);
  int* offsets = (int*)alloc((size_t)(M + 1) * 4);
  int* cursor = (int*)alloc((size_t)M * 4);
  int* srcs = (int*)alloc((size_t)E * 4);
  float* stats = (float*)alloc(4 * 128 * 4);
  float* sums = stats;
  float* sumsq = stats + 128;
  float* scale = stats + 256;
  float* shift = stats + 384;

  int nb = (M + 511) / 512;

  prep_kernel<<<2048, 256, 0, stream>>>(x, hbuf, counts, scale, shift, sums, sumsq, M);
  hist_kernel<<<(E + 255) / 256, 256, 0, stream>>>(dstp, counts, E);
  scan1_kernel<<<nb, 512, 0, stream>>>(counts, incl, bsums, M);
  scan2_kernel<<<1, 128, 0, stream>>>(bsums, nb);
  scan3_kernel<<<(M + 255) / 256, 256, 0, stream>>>(counts, incl, bsums, offsets, cursor, M);
  fill_kernel<<<(E + 255) / 256, 256, 0, stream>>>(srcp, dstp, cursor, srcs, E);
  prep_w_kernel<<<(L * 2 * 16384 + 255) / 256, 256, 0, stream>>>(W1, W2, WT, L * 2 * 16384);

  float invM = 1.0f / (float)M;
  int agg_grid = (M * 16 + 255) / 256;
  int mlp_grid = (M + 63) / 64;
  for (int l = 0; l < L; ++l) {
    for (int q = 0; q < 4; ++q) {
      agg_kernel<<<agg_grid, 256, 0, stream>>>(hbuf + (size_t)q * M * 16, offsets, srcs,
                                               scale + q * 32, shift + q * 32, aggbuf, M, q * 16);
    }
    mlp_kernel<<<mlp_grid, 256, 0, stream>>>(
        (const unsigned short*)aggbuf, WT + (size_t)(2 * l) * 16384, b1 + l * 128,
        WT + (size_t)(2 * l + 1) * 16384, b2 + l * 128, hbuf, sums, sumsq, M);
    bn_finalize_kernel<<<1, 128, 0, stream>>>(sums, sumsq, gamma + l * 128, beta + l * 128,
                                              scale, shift, invM);
  }

  pool_proj_kernel<<<G, 256, 0, stream>>>(hbuf, batch, scale, shift, Wp, bp, out, M);
}

// Round 5
// 480.534 us; speedup vs baseline: 1.2149x; 1.2149x over previous
//
#include <hip/hip_runtime.h>

// ---------------------------------------------------------------------------
// GIN encoder, fp16 feature path + MFMA, fused per-layer kernel.
// layer_kernel: per 64-row block:
//   phase A: CSR gather (2 rows in flight, unroll-4 each) + fused BN of the
//            PREVIOUS layer (scale*agg + (1+deg)*shift) -> swizzled LDS tile
//   GEMM1 (MFMA, W1^T reg frags) -> ReLU -> same LDS tile (swizzled)
//   GEMM2 -> bias+ReLU -> Hout (row-major fp16) + per-block column stats
//            written to pstat[bid] (NO contended global atomics)
// bn_stats_kernel (128 blocks): reduce pstat -> scale/shift for next layer.
// Last layer's BN folds into pool_proj_kernel.
// ---------------------------------------------------------------------------

typedef __attribute__((ext_vector_type(8))) _Float16 f16x8;
typedef __attribute__((ext_vector_type(4))) float f32x4;

static __device__ __forceinline__ float h2f(unsigned short u) {
  return (float)__builtin_bit_cast(_Float16, u);
}
static __device__ __forceinline__ unsigned short f2h(float f) {
  return __builtin_bit_cast(unsigned short, (_Float16)f);
}
static __device__ __forceinline__ float lo16(unsigned int v) { return h2f((unsigned short)(v & 0xffffu)); }
static __device__ __forceinline__ float hi16(unsigned int v) { return h2f((unsigned short)(v >> 16)); }

// ---- CSR build ----
__global__ __launch_bounds__(256) void hist_kernel(const int* __restrict__ dst,
                                                   int* __restrict__ counts, int E) {
  int e = blockIdx.x * 256 + threadIdx.x;
  if (e < E) atomicAdd(&counts[dst[e]], 1);
}

__global__ __launch_bounds__(512) void scan1_kernel(const int* __restrict__ counts,
                                                    int* __restrict__ incl,
                                                    int* __restrict__ bsums, int n) {
  __shared__ int buf[2][512];
  int t = threadIdx.x;
  int i = blockIdx.x * 512 + t;
  buf[0][t] = (i < n) ? counts[i] : 0;
  __syncthreads();
  int cur = 0;
  for (int off = 1; off < 512; off <<= 1) {
    buf[cur ^ 1][t] = buf[cur][t] + ((t >= off) ? buf[cur][t - off] : 0);
    __syncthreads();
    cur ^= 1;
  }
  if (i < n) incl[i] = buf[cur][t];
  if (t == 511) bsums[blockIdx.x] = buf[cur][511];
}

__global__ __launch_bounds__(128) void scan2_kernel(int* __restrict__ bsums, int nb) {
  __shared__ int buf[2][128];
  int t = threadIdx.x;
  int v = (t < nb) ? bsums[t] : 0;
  buf[0][t] = v;
  __syncthreads();
  int cur = 0;
  for (int off = 1; off < 128; off <<= 1) {
    buf[cur ^ 1][t] = buf[cur][t] + ((t >= off) ? buf[cur][t - off] : 0);
    __syncthreads();
    cur ^= 1;
  }
  if (t < nb) bsums[t] = buf[cur][t] - v;  // exclusive
}

__global__ __launch_bounds__(256) void scan3_kernel(const int* __restrict__ counts,
                                                    const int* __restrict__ incl,
                                                    const int* __restrict__ bsums,
                                                    int* __restrict__ offsets,
                                                    int* __restrict__ cursor, int n) {
  int i = blockIdx.x * 256 + threadIdx.x;
  if (i < n) {
    int total = bsums[i >> 9] + incl[i];
    offsets[i + 1] = total;
    cursor[i] = total - counts[i];
  }
  if (i == 0) offsets[0] = 0;
}

__global__ __launch_bounds__(256) void fill_kernel(const int* __restrict__ src,
                                                   const int* __restrict__ dst,
                                                   int* cursor, int* __restrict__ srcs, int E) {
  int e = blockIdx.x * 256 + threadIdx.x;
  if (e < E) {
    int p = atomicAdd(&cursor[dst[e]], 1);
    srcs[p] = src[e];
  }
}

// ---- prep: x -> fp16 row-major (uint-packed); zero counts; init affine ----
__global__ __launch_bounds__(256) void prep_kernel(const float* __restrict__ x,
                                                   unsigned int* __restrict__ h,
                                                   int* __restrict__ counts,
                                                   float* __restrict__ scale,
                                                   float* __restrict__ shift, int M) {
  int stride = gridDim.x * 256;
  int tid = blockIdx.x * 256 + threadIdx.x;
  const float2* x2 = (const float2*)x;
  int total = M * 64;
  for (int i = tid; i < total; i += stride) {
    float2 v = x2[i];
    h[i] = (unsigned int)f2h(v.x) | ((unsigned int)f2h(v.y) << 16);
  }
  for (int i = tid; i < M; i += stride) counts[i] = 0;
  if (tid < 128) { scale[tid] = 1.f; shift[tid] = 0.f; }
}

// WT[m][n][k] = f16(W_m[k][n]), m in [0, 2L): even=W1 layer m/2, odd=W2 layer m/2
__global__ __launch_bounds__(256) void prep_w_kernel(const float* __restrict__ W1,
                                                     const float* __restrict__ W2,
                                                     unsigned short* __restrict__ WT, int total) {
  int idx = blockIdx.x * 256 + threadIdx.x;
  if (idx >= total) return;
  int m = idx >> 14;
  int rem = idx & 16383;
  int n = rem >> 7, k = rem & 127;
  const float* W = ((m & 1) == 0) ? (W1 + (size_t)(m >> 1) * 16384)
                                  : (W2 + (size_t)(m >> 1) * 16384);
  WT[idx] = f2h(W[k * 128 + n]);
}

// ---- fused layer: gather+BN -> LDS -> GEMM1 -> LDS -> GEMM2 -> Hout+stats ----
// LDS tile swizzle: fp16 col c of row rl lives at byte (rl*256 + ((c*2) ^ ((rl&7)<<4))).
// MFMA frag layouts (m89-verified, used in passing rounds 3/4):
//   A/B: lane holds X[(l&15)][ks*32 + (l>>4)*8 + j]; C/D: col=lane&15, row=(lane>>4)*4+reg.
__global__ __launch_bounds__(256) void layer_kernel(
    const unsigned int* __restrict__ Hin,  // M x 64 uints (fp16x2, row-major)
    const int* __restrict__ offsets, const int* __restrict__ srcs,
    const float* __restrict__ scale, const float* __restrict__ shift,
    const unsigned short* __restrict__ WT1, const float* __restrict__ b1,
    const unsigned short* __restrict__ WT2, const float* __restrict__ b2,
    unsigned short* __restrict__ Hout,  // M x 128 fp16 row-major
    float* __restrict__ pstat, int M) {
  __shared__ unsigned short sT[64 * 128];
  __shared__ float s_sum[128], s_sq[128];
  int t = threadIdx.x;
  if (t < 128) { s_sum[t] = 0.f; s_sq[t] = 0.f; }
  int wave = t >> 6, lane = t & 63;
  int row0 = blockIdx.x * 64;
  char* sTb = (char*)sT;
  float sc0 = scale[2 * lane], sc1 = scale[2 * lane + 1];
  float sh0 = shift[2 * lane], sh1 = shift[2 * lane + 1];

  // ---- phase A: gather + prev-layer BN, 2 rows in flight ----
  for (int i = 0; i < 16; i += 2) {
    int rA = row0 + wave * 16 + i;
    int rB = rA + 1;
    float axA = 0.f, ayA = 0.f, axB = 0.f, ayB = 0.f;
    int eA = 0, eA1 = 0, eB = 0, eB1 = 0;
    if (rA < M) {
      eA = offsets[rA]; eA1 = offsets[rA + 1];
      unsigned int s = Hin[(size_t)rA * 64 + lane];
      axA = lo16(s); ayA = hi16(s);
    }
    if (rB < M) {
      eB = offsets[rB]; eB1 = offsets[rB + 1];
      unsigned int s = Hin[(size_t)rB * 64 + lane];
      axB = lo16(s); ayB = hi16(s);
    }
    int dA = eA1 - eA, dB = eB1 - eB;
    while (eA + 4 <= eA1 && eB + 4 <= eB1) {
      int a0 = srcs[eA], a1 = srcs[eA + 1], a2 = srcs[eA + 2], a3 = srcs[eA + 3];
      int c0 = srcs[eB], c1 = srcs[eB + 1], c2 = srcs[eB + 2], c3 = srcs[eB + 3];
      unsigned int vA0 = Hin[(size_t)a0 * 64 + lane];
      unsigned int vA1 = Hin[(size_t)a1 * 64 + lane];
      unsigned int vA2 = Hin[(size_t)a2 * 64 + lane];
      unsigned int vA3 = Hin[(size_t)a3 * 64 + lane];
      unsigned int vB0 = Hin[(size_t)c0 * 64 + lane];
      unsigned int vB1 = Hin[(size_t)c1 * 64 + lane];
      unsigned int vB2 = Hin[(size_t)c2 * 64 + lane];
      unsigned int vB3 = Hin[(size_t)c3 * 64 + lane];
      axA += lo16(vA0) + lo16(vA1) + lo16(vA2) + lo16(vA3);
      ayA += hi16(vA0) + hi16(vA1) + hi16(vA2) + hi16(vA3);
      axB += lo16(vB0) + lo16(vB1) + lo16(vB2) + lo16(vB3);
      ayB += hi16(vB0) + hi16(vB1) + hi16(vB2) + hi16(vB3);
      eA += 4; eB += 4;
    }
    while (eA + 4 <= eA1) {
      int a0 = srcs[eA], a1 = srcs[eA + 1], a2 = srcs[eA + 2], a3 = srcs[eA + 3];
      unsigned int v0 = Hin[(size_t)a0 * 64 + lane];
      unsigned int v1 = Hin[(size_t)a1 * 64 + lane];
      unsigned int v2 = Hin[(size_t)a2 * 64 + lane];
      unsigned int v3 = Hin[(size_t)a3 * 64 + lane];
      axA += lo16(v0) + lo16(v1) + lo16(v2) + lo16(v3);
      ayA += hi16(v0) + hi16(v1) + hi16(v2) + hi16(v3);
      eA += 4;
    }
    while (eB + 4 <= eB1) {
      int c0 = srcs[eB], c1 = srcs[eB + 1], c2 = srcs[eB + 2], c3 = srcs[eB + 3];
      unsigned int v0 = Hin[(size_t)c0 * 64 + lane];
      unsigned int v1 = Hin[(size_t)c1 * 64 + lane];
      unsigned int v2 = Hin[(size_t)c2 * 64 + lane];
      unsigned int v3 = Hin[(size_t)c3 * 64 + lane];
      axB += lo16(v0) + lo16(v1) + lo16(v2) + lo16(v3);
      ayB += hi16(v0) + hi16(v1) + hi16(v2) + hi16(v3);
      eB += 4;
    }
    for (; eA < eA1; ++eA) {
      unsigned int v = Hin[(size_t)srcs[eA] * 64 + lane];
      axA += lo16(v); ayA += hi16(v);
    }
    for (; eB < eB1; ++eB) {
      unsigned int v = Hin[(size_t)srcs[eB] * 64 + lane];
      axB += lo16(v); ayB += hi16(v);
    }
    int rlA = wave * 16 + i, rlB = rlA + 1;
    float dA1 = (float)(dA + 1), dB1 = (float)(dB + 1);
    unsigned int oA = (unsigned int)f2h(axA * sc0 + dA1 * sh0) |
                      ((unsigned int)f2h(ayA * sc1 + dA1 * sh1) << 16);
    unsigned int oB = (unsigned int)f2h(axB * sc0 + dB1 * sh0) |
                      ((unsigned int)f2h(ayB * sc1 + dB1 * sh1) << 16);
    *(unsigned int*)(sTb + rlA * 256 + ((lane * 4) ^ ((rlA & 7) << 4))) = (rA < M) ? oA : 0u;
    *(unsigned int*)(sTb + rlB * 256 + ((lane * 4) ^ ((rlB & 7) << 4))) = (rB < M) ? oB : 0u;
  }
  __syncthreads();

  // ---- GEMM1: A from LDS tile, B = WT1 frags from global ----
  int lrow = lane & 15, hi = lane >> 4;
  int lk = hi * 8;
  int rl = wave * 16 + lrow;
  f16x8 af[4];
#pragma unroll
  for (int ks = 0; ks < 4; ++ks)
    af[ks] = *(const f16x8*)(sTb + rl * 256 + ((ks * 64 + hi * 16) ^ ((rl & 7) << 4)));

  f32x4 acc[8];
#pragma unroll
  for (int n = 0; n < 8; ++n) acc[n] = (f32x4){0.f, 0.f, 0.f, 0.f};
#pragma unroll
  for (int ks = 0; ks < 4; ++ks) {
    f16x8 bf[8];
#pragma unroll
    for (int n = 0; n < 8; ++n)
      bf[n] = *(const f16x8*)(WT1 + (size_t)(n * 16 + lrow) * 128 + ks * 32 + lk);
#pragma unroll
    for (int n = 0; n < 8; ++n)
      acc[n] = __builtin_amdgcn_mfma_f32_16x16x32_f16(af[ks], bf[n], acc[n], 0, 0, 0);
  }
  __syncthreads();  // all waves done reading sT before overwrite

  // epilogue1: bias+ReLU -> same LDS tile (swizzled)
#pragma unroll
  for (int n = 0; n < 8; ++n) {
    int col = n * 16 + lrow;
    float bia = b1[col];
#pragma unroll
    for (int r = 0; r < 4; ++r) {
      int rlw = wave * 16 + hi * 4 + r;
      float v = fmaxf(acc[n][r] + bia, 0.f);
      *(unsigned short*)(sTb + rlw * 256 + ((col * 2) ^ ((rlw & 7) << 4))) = f2h(v);
    }
  }
  __syncthreads();

  // ---- GEMM2 ----
#pragma unroll
  for (int ks = 0; ks < 4; ++ks)
    af[ks] = *(const f16x8*)(sTb + rl * 256 + ((ks * 64 + hi * 16) ^ ((rl & 7) << 4)));
#pragma unroll
  for (int n = 0; n < 8; ++n) acc[n] = (f32x4){0.f, 0.f, 0.f, 0.f};
#pragma unroll
  for (int ks = 0; ks < 4; ++ks) {
    f16x8 bf[8];
#pragma unroll
    for (int n = 0; n < 8; ++n)
      bf[n] = *(const f16x8*)(WT2 + (size_t)(n * 16 + lrow) * 128 + ks * 32 + lk);
#pragma unroll
    for (int n = 0; n < 8; ++n)
      acc[n] = __builtin_amdgcn_mfma_f32_16x16x32_f16(af[ks], bf[n], acc[n], 0, 0, 0);
  }

  // epilogue2: bias+ReLU -> Hout + per-block column stats (no global atomics)
  int rbase = row0 + wave * 16 + hi * 4;
#pragma unroll
  for (int n = 0; n < 8; ++n) {
    int col = n * 16 + lrow;
    float bia = b2[col];
    float cs = 0.f, cq = 0.f;
#pragma unroll
    for (int r = 0; r < 4; ++r) {
      int rr = rbase + r;
      float v = fmaxf(acc[n][r] + bia, 0.f);
      if (rr < M) {
        Hout[(size_t)rr * 128 + col] = f2h(v);
        cs += v;
        cq += v * v;
      }
    }
    cs += __shfl_xor(cs, 16); cs += __shfl_xor(cs, 32);
    cq += __shfl_xor(cq, 16); cq += __shfl_xor(cq, 32);
    if (hi == 0) {
      atomicAdd(&s_sum[col], cs);  // LDS atomics only
      atomicAdd(&s_sq[col], cq);
    }
  }
  __syncthreads();
  if (t < 128) {
    float* p = pstat + (size_t)blockIdx.x * 256;
    p[t] = s_sum[t];
    p[t + 128] = s_sq[t];
  }
}

// reduce per-block partials -> scale/shift for the next layer (one block per column)
__global__ __launch_bounds__(256) void bn_stats_kernel(const float* __restrict__ pstat, int nb,
                                                       const float* __restrict__ gamma,
                                                       const float* __restrict__ beta,
                                                       float* __restrict__ scale,
                                                       float* __restrict__ shift, float invM) {
  int c = blockIdx.x;
  int t = threadIdx.x;
  float s = 0.f, q = 0.f;
  for (int b = t; b < nb; b += 256) {
    const float* p = pstat + (size_t)b * 256;
    s += p[c];
    q += p[c + 128];
  }
#pragma unroll
  for (int off = 1; off < 64; off <<= 1) {
    s += __shfl_xor(s, off);
    q += __shfl_xor(q, off);
  }
  __shared__ float rs[4], rq[4];
  if ((t & 63) == 0) { rs[t >> 6] = s; rq[t >> 6] = q; }
  __syncthreads();
  if (t == 0) {
    float S = rs[0] + rs[1] + rs[2] + rs[3];
    float Q = rq[0] + rq[1] + rq[2] + rq[3];
    float mean = S * invM;
    float var = fmaxf(Q * invM - mean * mean, 0.f);
    float sc = gamma[c] * rsqrtf(var + 1e-5f);
    scale[c] = sc;
    shift[c] = beta[c] - mean * sc;
  }
}

// ---- fused pool (last layer BN) + projection ----
__global__ __launch_bounds__(256) void pool_proj_kernel(const unsigned int* __restrict__ H,
                                                        const int* __restrict__ batch,
                                                        const float* __restrict__ scale,
                                                        const float* __restrict__ shift,
                                                        const float* __restrict__ Wp,
                                                        const float* __restrict__ bp,
                                                        float* __restrict__ out, int M) {
  int gid = blockIdx.x;
  int lo = 0, hi = M;
  while (lo < hi) { int mid = (lo + hi) >> 1; if (batch[mid] < gid) lo = mid + 1; else hi = mid; }
  int s = lo;
  lo = 0; hi = M;
  while (lo < hi) { int mid = (lo + hi) >> 1; if (batch[mid] < gid + 1) lo = mid + 1; else hi = mid; }
  int e = lo;
  int t = threadIdx.x;
  int cp = t & 63, rs_ = t >> 6;  // col-pair, row phase
  float ax = 0.f, ay = 0.f;
  for (int r = s + rs_; r < e; r += 4) {
    unsigned int v = H[(size_t)r * 64 + cp];
    ax += lo16(v);
    ay += hi16(v);
  }
  __shared__ float redx[256], redy[256];
  __shared__ float g[128];
  redx[t] = ax;
  redy[t] = ay;
  __syncthreads();
  if (t < 128) {
    int cpp = t >> 1;
    float sum;
    if (t & 1)
      sum = redy[cpp] + redy[64 + cpp] + redy[128 + cpp] + redy[192 + cpp];
    else
      sum = redx[cpp] + redx[64 + cpp] + redx[128 + cpp] + redx[192 + cpp];
    g[t] = sum * scale[t] + (float)(e - s) * shift[t];
  }
  __syncthreads();
  if (t < 128) {
    float a2 = bp[t];
#pragma unroll 8
    for (int k = 0; k < 128; ++k) a2 = fmaf(g[k], Wp[k * 128 + t], a2);
    out[gid * 128 + t] = fmaxf(a2, 0.f);
  }
}

extern "C" void kernel_launch(void* const* d_in, const int* in_sizes, int n_in,
                              void* d_out, int out_size, void* d_ws, size_t ws_size,
                              hipStream_t stream) {
  const float* x = (const float*)d_in[0];
  const int* ei = (const int*)d_in[1];
  const int* batch = (const int*)d_in[2];
  const float* W1 = (const float*)d_in[3];
  const float* b1 = (const float*)d_in[4];
  const float* W2 = (const float*)d_in[5];
  const float* b2 = (const float*)d_in[6];
  const float* gamma = (const float*)d_in[7];
  const float* beta = (const float*)d_in[8];
  const float* Wp = (const float*)d_in[9];
  const float* bp = (const float*)d_in[10];
  float* out = (float*)d_out;

  int M = in_sizes[0] / 128;
  int E = in_sizes[1] / 2;
  int L = in_sizes[3] / (128 * 128);
  int G = out_size / 128;
  const int* srcp = ei;
  const int* dstp = ei + E;

  char* w = (char*)d_ws;
  auto alloc = [&](size_t bytes) {
    char* p = w;
    w += (bytes + 255) & ~(size_t)255;
    return p;
  };
  int nblk = (M + 63) / 64;
  unsigned int* bufA = (unsigned int*)alloc((size_t)M * 64 * 4);
  unsigned int* bufB = (unsigned int*)alloc((size_t)M * 64 * 4);
  unsigned short* WT = (unsigned short*)alloc((size_t)L * 2 * 16384 * 2);
  int* counts = (int*)alloc((size_t)M * 4);
  int* incl = (int*)alloc((size_t)M * 4);
  int* bsums = (int*)alloc(128 * 4);
  int* offsets = (int*)alloc((size_t)(M + 1) * 4);
  int* cursor = (int*)alloc((size_t)M * 4);
  int* srcs = (int*)alloc((size_t)E * 4);
  float* pstat = (float*)alloc((size_t)nblk * 256 * 4);
  float* stats = (float*)alloc(2 * 128 * 4);
  float* scale = stats;
  float* shift = stats + 128;

  int nb = (M + 511) / 512;

  prep_kernel<<<2048, 256, 0, stream>>>(x, bufA, counts, scale, shift, M);
  hist_kernel<<<(E + 255) / 256, 256, 0, stream>>>(dstp, counts, E);
  scan1_kernel<<<nb, 512, 0, stream>>>(counts, incl, bsums, M);
  scan2_kernel<<<1, 128, 0, stream>>>(bsums, nb);
  scan3_kernel<<<(M + 255) / 256, 256, 0, stream>>>(counts, incl, bsums, offsets, cursor, M);
  fill_kernel<<<(E + 255) / 256, 256, 0, stream>>>(srcp, dstp, cursor, srcs, E);
  prep_w_kernel<<<(L * 2 * 16384 + 255) / 256, 256, 0, stream>>>(W1, W2, WT, L * 2 * 16384);

  float invM = 1.0f / (float)M;
  unsigned int* cur = bufA;
  unsigned int* nxt = bufB;
  for (int l = 0; l < L; ++l) {
    layer_kernel<<<nblk, 256, 0, stream>>>(
        cur, offsets, srcs, scale, shift, WT + (size_t)(2 * l) * 16384, b1 + l * 128,
        WT + (size_t)(2 * l + 1) * 16384, b2 + l * 128, (unsigned short*)nxt, pstat, M);
    bn_stats_kernel<<<128, 256, 0, stream>>>(pstat, nblk, gamma + l * 128, beta + l * 128,
                                             scale, shift, invM);
    unsigned int* tmp = cur; cur = nxt; nxt = tmp;
  }

  pool_proj_kernel<<<G, 256, 0, stream>>>(cur, batch, scale, shift, Wp, bp, out, M);
}

// Round 6
// 414.100 us; speedup vs baseline: 1.4098x; 1.1604x over previous
//
#include <hip/hip_runtime.h>

// ---------------------------------------------------------------------------
// GIN encoder, fp16 feature path + MFMA, fused per-layer kernel (512 thr).
// layer_kernel: per 64-row block, 8 waves:
//   phase A: CSR gather (each wave 8 rows; 2 rows in flight, unroll-4) +
//            fused BN of the PREVIOUS layer -> swizzled LDS tile
//   GEMM1: 8-way wave split (wr=wave&3 rows, wc=wave>>2 col-half) -> ReLU
//          -> same LDS tile
//   GEMM2: same split -> bias+ReLU -> Hout + per-block column stats -> pstat
// bn_stats_kernel reduces pstat -> scale/shift. Last layer BN folds into
// pool_proj_kernel.
// 512 threads (vs 256 in round 5): occupancy was 28% and the gather is
// latency-bound; 8 waves/block at <=64 VGPR gives ~24 waves/CU resident.
// ---------------------------------------------------------------------------

typedef __attribute__((ext_vector_type(8))) _Float16 f16x8;
typedef __attribute__((ext_vector_type(4))) float f32x4;

static __device__ __forceinline__ float h2f(unsigned short u) {
  return (float)__builtin_bit_cast(_Float16, u);
}
static __device__ __forceinline__ unsigned short f2h(float f) {
  return __builtin_bit_cast(unsigned short, (_Float16)f);
}
static __device__ __forceinline__ float lo16(unsigned int v) { return h2f((unsigned short)(v & 0xffffu)); }
static __device__ __forceinline__ float hi16(unsigned int v) { return h2f((unsigned short)(v >> 16)); }

// ---- CSR build ----
__global__ __launch_bounds__(256) void hist_kernel(const int* __restrict__ dst,
                                                   int* __restrict__ counts, int E) {
  int e = blockIdx.x * 256 + threadIdx.x;
  if (e < E) atomicAdd(&counts[dst[e]], 1);
}

__global__ __launch_bounds__(512) void scan1_kernel(const int* __restrict__ counts,
                                                    int* __restrict__ incl,
                                                    int* __restrict__ bsums, int n) {
  __shared__ int buf[2][512];
  int t = threadIdx.x;
  int i = blockIdx.x * 512 + t;
  buf[0][t] = (i < n) ? counts[i] : 0;
  __syncthreads();
  int cur = 0;
  for (int off = 1; off < 512; off <<= 1) {
    buf[cur ^ 1][t] = buf[cur][t] + ((t >= off) ? buf[cur][t - off] : 0);
    __syncthreads();
    cur ^= 1;
  }
  if (i < n) incl[i] = buf[cur][t];
  if (t == 511) bsums[blockIdx.x] = buf[cur][511];
}

__global__ __launch_bounds__(128) void scan2_kernel(int* __restrict__ bsums, int nb) {
  __shared__ int buf[2][128];
  int t = threadIdx.x;
  int v = (t < nb) ? bsums[t] : 0;
  buf[0][t] = v;
  __syncthreads();
  int cur = 0;
  for (int off = 1; off < 128; off <<= 1) {
    buf[cur ^ 1][t] = buf[cur][t] + ((t >= off) ? buf[cur][t - off] : 0);
    __syncthreads();
    cur ^= 1;
  }
  if (t < nb) bsums[t] = buf[cur][t] - v;  // exclusive
}

__global__ __launch_bounds__(256) void scan3_kernel(const int* __restrict__ counts,
                                                    const int* __restrict__ incl,
                                                    const int* __restrict__ bsums,
                                                    int* __restrict__ offsets,
                                                    int* __restrict__ cursor, int n) {
  int i = blockIdx.x * 256 + threadIdx.x;
  if (i < n) {
    int total = bsums[i >> 9] + incl[i];
    offsets[i + 1] = total;
    cursor[i] = total - counts[i];
  }
  if (i == 0) offsets[0] = 0;
}

__global__ __launch_bounds__(256) void fill_kernel(const int* __restrict__ src,
                                                   const int* __restrict__ dst,
                                                   int* cursor, int* __restrict__ srcs, int E) {
  int e = blockIdx.x * 256 + threadIdx.x;
  if (e < E) {
    int p = atomicAdd(&cursor[dst[e]], 1);
    srcs[p] = src[e];
  }
}

// ---- prep: x -> fp16 row-major (uint-packed); zero counts; init affine ----
__global__ __launch_bounds__(256) void prep_kernel(const float* __restrict__ x,
                                                   unsigned int* __restrict__ h,
                                                   int* __restrict__ counts,
                                                   float* __restrict__ scale,
                                                   float* __restrict__ shift, int M) {
  int stride = gridDim.x * 256;
  int tid = blockIdx.x * 256 + threadIdx.x;
  const float2* x2 = (const float2*)x;
  int total = M * 64;
  for (int i = tid; i < total; i += stride) {
    float2 v = x2[i];
    h[i] = (unsigned int)f2h(v.x) | ((unsigned int)f2h(v.y) << 16);
  }
  for (int i = tid; i < M; i += stride) counts[i] = 0;
  if (tid < 128) { scale[tid] = 1.f; shift[tid] = 0.f; }
}

// WT[m][n][k] = f16(W_m[k][n]), m in [0, 2L): even=W1 layer m/2, odd=W2 layer m/2
__global__ __launch_bounds__(256) void prep_w_kernel(const float* __restrict__ W1,
                                                     const float* __restrict__ W2,
                                                     unsigned short* __restrict__ WT, int total) {
  int idx = blockIdx.x * 256 + threadIdx.x;
  if (idx >= total) return;
  int m = idx >> 14;
  int rem = idx & 16383;
  int n = rem >> 7, k = rem & 127;
  const float* W = ((m & 1) == 0) ? (W1 + (size_t)(m >> 1) * 16384)
                                  : (W2 + (size_t)(m >> 1) * 16384);
  WT[idx] = f2h(W[k * 128 + n]);
}

// ---- fused layer: gather+BN -> LDS -> GEMM1 -> LDS -> GEMM2 -> Hout+stats ----
// LDS tile swizzle: fp16 col c of row rl lives at byte (rl*256 + ((c*2) ^ ((rl&7)<<4))).
// MFMA frag layouts (m89-verified, used in passing rounds 3/4/5):
//   A/B: lane holds X[(l&15)][ks*32 + (l>>4)*8 + j]; C/D: col=lane&15, row=(lane>>4)*4+reg.
__global__ __launch_bounds__(512, 6) void layer_kernel(
    const unsigned int* __restrict__ Hin,  // M x 64 uints (fp16x2, row-major)
    const int* __restrict__ offsets, const int* __restrict__ srcs,
    const float* __restrict__ scale, const float* __restrict__ shift,
    const unsigned short* __restrict__ WT1, const float* __restrict__ b1,
    const unsigned short* __restrict__ WT2, const float* __restrict__ b2,
    unsigned short* __restrict__ Hout,  // M x 128 fp16 row-major
    float* __restrict__ pstat, int M) {
  __shared__ unsigned short sT[64 * 128];
  __shared__ float s_sum[128], s_sq[128];
  int t = threadIdx.x;
  if (t < 128) { s_sum[t] = 0.f; s_sq[t] = 0.f; }
  int wave = t >> 6, lane = t & 63;
  int row0 = blockIdx.x * 64;
  char* sTb = (char*)sT;
  float sc0 = scale[2 * lane], sc1 = scale[2 * lane + 1];
  float sh0 = shift[2 * lane], sh1 = shift[2 * lane + 1];

  // ---- phase A: gather + prev-layer BN; each wave 8 rows, 2 in flight ----
  for (int i = 0; i < 8; i += 2) {
    int rA = row0 + wave * 8 + i;
    int rB = rA + 1;
    float axA = 0.f, ayA = 0.f, axB = 0.f, ayB = 0.f;
    int eA = 0, eA1 = 0, eB = 0, eB1 = 0;
    if (rA < M) {
      eA = offsets[rA]; eA1 = offsets[rA + 1];
      unsigned int s = Hin[(size_t)rA * 64 + lane];
      axA = lo16(s); ayA = hi16(s);
    }
    if (rB < M) {
      eB = offsets[rB]; eB1 = offsets[rB + 1];
      unsigned int s = Hin[(size_t)rB * 64 + lane];
      axB = lo16(s); ayB = hi16(s);
    }
    int dA = eA1 - eA, dB = eB1 - eB;
    while (eA + 4 <= eA1 && eB + 4 <= eB1) {
      int a0 = srcs[eA], a1 = srcs[eA + 1], a2 = srcs[eA + 2], a3 = srcs[eA + 3];
      int c0 = srcs[eB], c1 = srcs[eB + 1], c2 = srcs[eB + 2], c3 = srcs[eB + 3];
      unsigned int vA0 = Hin[(size_t)a0 * 64 + lane];
      unsigned int vA1 = Hin[(size_t)a1 * 64 + lane];
      unsigned int vA2 = Hin[(size_t)a2 * 64 + lane];
      unsigned int vA3 = Hin[(size_t)a3 * 64 + lane];
      unsigned int vB0 = Hin[(size_t)c0 * 64 + lane];
      unsigned int vB1 = Hin[(size_t)c1 * 64 + lane];
      unsigned int vB2 = Hin[(size_t)c2 * 64 + lane];
      unsigned int vB3 = Hin[(size_t)c3 * 64 + lane];
      axA += lo16(vA0) + lo16(vA1) + lo16(vA2) + lo16(vA3);
      ayA += hi16(vA0) + hi16(vA1) + hi16(vA2) + hi16(vA3);
      axB += lo16(vB0) + lo16(vB1) + lo16(vB2) + lo16(vB3);
      ayB += hi16(vB0) + hi16(vB1) + hi16(vB2) + hi16(vB3);
      eA += 4; eB += 4;
    }
    while (eA + 4 <= eA1) {
      int a0 = srcs[eA], a1 = srcs[eA + 1], a2 = srcs[eA + 2], a3 = srcs[eA + 3];
      unsigned int v0 = Hin[(size_t)a0 * 64 + lane];
      unsigned int v1 = Hin[(size_t)a1 * 64 + lane];
      unsigned int v2 = Hin[(size_t)a2 * 64 + lane];
      unsigned int v3 = Hin[(size_t)a3 * 64 + lane];
      axA += lo16(v0) + lo16(v1) + lo16(v2) + lo16(v3);
      ayA += hi16(v0) + hi16(v1) + hi16(v2) + hi16(v3);
      eA += 4;
    }
    while (eB + 4 <= eB1) {
      int c0 = srcs[eB], c1 = srcs[eB + 1], c2 = srcs[eB + 2], c3 = srcs[eB + 3];
      unsigned int v0 = Hin[(size_t)c0 * 64 + lane];
      unsigned int v1 = Hin[(size_t)c1 * 64 + lane];
      unsigned int v2 = Hin[(size_t)c2 * 64 + lane];
      unsigned int v3 = Hin[(size_t)c3 * 64 + lane];
      axB += lo16(v0) + lo16(v1) + lo16(v2) + lo16(v3);
      ayB += hi16(v0) + hi16(v1) + hi16(v2) + hi16(v3);
      eB += 4;
    }
    for (; eA < eA1; ++eA) {
      unsigned int v = Hin[(size_t)srcs[eA] * 64 + lane];
      axA += lo16(v); ayA += hi16(v);
    }
    for (; eB < eB1; ++eB) {
      unsigned int v = Hin[(size_t)srcs[eB] * 64 + lane];
      axB += lo16(v); ayB += hi16(v);
    }
    int rlA = wave * 8 + i, rlB = rlA + 1;
    float dA1 = (float)(dA + 1), dB1 = (float)(dB + 1);
    unsigned int oA = (unsigned int)f2h(axA * sc0 + dA1 * sh0) |
                      ((unsigned int)f2h(ayA * sc1 + dA1 * sh1) << 16);
    unsigned int oB = (unsigned int)f2h(axB * sc0 + dB1 * sh0) |
                      ((unsigned int)f2h(ayB * sc1 + dB1 * sh1) << 16);
    *(unsigned int*)(sTb + rlA * 256 + ((lane * 4) ^ ((rlA & 7) << 4))) = (rA < M) ? oA : 0u;
    *(unsigned int*)(sTb + rlB * 256 + ((lane * 4) ^ ((rlB & 7) << 4))) = (rB < M) ? oB : 0u;
  }
  __syncthreads();

  // ---- 8-way wave split: wr = row quadrant (16 rows), wc = col half (64) ----
  int wr = wave & 3, wc = wave >> 2;
  int lrow = lane & 15, hi = lane >> 4;
  int lk = hi * 8;
  int rl = wr * 16 + lrow;

  // GEMM1
  f16x8 af[4];
#pragma unroll
  for (int ks = 0; ks < 4; ++ks)
    af[ks] = *(const f16x8*)(sTb + rl * 256 + ((ks * 64 + hi * 16) ^ ((rl & 7) << 4)));
  f32x4 acc[4];
#pragma unroll
  for (int n = 0; n < 4; ++n) acc[n] = (f32x4){0.f, 0.f, 0.f, 0.f};
#pragma unroll
  for (int ks = 0; ks < 4; ++ks) {
    f16x8 bf[4];
#pragma unroll
    for (int n = 0; n < 4; ++n)
      bf[n] = *(const f16x8*)(WT1 + (size_t)(wc * 64 + n * 16 + lrow) * 128 + ks * 32 + lk);
#pragma unroll
    for (int n = 0; n < 4; ++n)
      acc[n] = __builtin_amdgcn_mfma_f32_16x16x32_f16(af[ks], bf[n], acc[n], 0, 0, 0);
  }
  __syncthreads();  // all waves done reading sT before overwrite

  // epilogue1: bias+ReLU -> same LDS tile (swizzled)
#pragma unroll
  for (int n = 0; n < 4; ++n) {
    int col = wc * 64 + n * 16 + lrow;
    float bia = b1[col];
#pragma unroll
    for (int r = 0; r < 4; ++r) {
      int rlw = wr * 16 + hi * 4 + r;
      float v = fmaxf(acc[n][r] + bia, 0.f);
      *(unsigned short*)(sTb + rlw * 256 + ((col * 2) ^ ((rlw & 7) << 4))) = f2h(v);
    }
  }
  __syncthreads();

  // ---- GEMM2 ----
#pragma unroll
  for (int ks = 0; ks < 4; ++ks)
    af[ks] = *(const f16x8*)(sTb + rl * 256 + ((ks * 64 + hi * 16) ^ ((rl & 7) << 4)));
#pragma unroll
  for (int n = 0; n < 4; ++n) acc[n] = (f32x4){0.f, 0.f, 0.f, 0.f};
#pragma unroll
  for (int ks = 0; ks < 4; ++ks) {
    f16x8 bf[4];
#pragma unroll
    for (int n = 0; n < 4; ++n)
      bf[n] = *(const f16x8*)(WT2 + (size_t)(wc * 64 + n * 16 + lrow) * 128 + ks * 32 + lk);
#pragma unroll
    for (int n = 0; n < 4; ++n)
      acc[n] = __builtin_amdgcn_mfma_f32_16x16x32_f16(af[ks], bf[n], acc[n], 0, 0, 0);
  }

  // epilogue2: bias+ReLU -> Hout + per-block column stats (LDS atomics only)
  int rbase = row0 + wr * 16 + hi * 4;
#pragma unroll
  for (int n = 0; n < 4; ++n) {
    int col = wc * 64 + n * 16 + lrow;
    float bia = b2[col];
    float cs = 0.f, cq = 0.f;
#pragma unroll
    for (int r = 0; r < 4; ++r) {
      int rr = rbase + r;
      float v = fmaxf(acc[n][r] + bia, 0.f);
      if (rr < M) {
        Hout[(size_t)rr * 128 + col] = f2h(v);
        cs += v;
        cq += v * v;
      }
    }
    cs += __shfl_xor(cs, 16); cs += __shfl_xor(cs, 32);
    cq += __shfl_xor(cq, 16); cq += __shfl_xor(cq, 32);
    if (hi == 0) {
      atomicAdd(&s_sum[col], cs);
      atomicAdd(&s_sq[col], cq);
    }
  }
  __syncthreads();
  if (t < 128) {
    float* p = pstat + (size_t)blockIdx.x * 256;
    p[t] = s_sum[t];
    p[t + 128] = s_sq[t];
  }
}

// reduce per-block partials -> scale/shift for the next layer (one block per column)
__global__ __launch_bounds__(256) void bn_stats_kernel(const float* __restrict__ pstat, int nb,
                                                       const float* __restrict__ gamma,
                                                       const float* __restrict__ beta,
                                                       float* __restrict__ scale,
                                                       float* __restrict__ shift, float invM) {
  int c = blockIdx.x;
  int t = threadIdx.x;
  float s = 0.f, q = 0.f;
  for (int b = t; b < nb; b += 256) {
    const float* p = pstat + (size_t)b * 256;
    s += p[c];
    q += p[c + 128];
  }
#pragma unroll
  for (int off = 1; off < 64; off <<= 1) {
    s += __shfl_xor(s, off);
    q += __shfl_xor(q, off);
  }
  __shared__ float rs[4], rq[4];
  if ((t & 63) == 0) { rs[t >> 6] = s; rq[t >> 6] = q; }
  __syncthreads();
  if (t == 0) {
    float S = rs[0] + rs[1] + rs[2] + rs[3];
    float Q = rq[0] + rq[1] + rq[2] + rq[3];
    float mean = S * invM;
    float var = fmaxf(Q * invM - mean * mean, 0.f);
    float sc = gamma[c] * rsqrtf(var + 1e-5f);
    scale[c] = sc;
    shift[c] = beta[c] - mean * sc;
  }
}

// ---- fused pool (last layer BN) + projection ----
__global__ __launch_bounds__(256) void pool_proj_kernel(const unsigned int* __restrict__ H,
                                                        const int* __restrict__ batch,
                                                        const float* __restrict__ scale,
                                                        const float* __restrict__ shift,
                                                        const float* __restrict__ Wp,
                                                        const float* __restrict__ bp,
                                                        float* __restrict__ out, int M) {
  int gid = blockIdx.x;
  int lo = 0, hi = M;
  while (lo < hi) { int mid = (lo + hi) >> 1; if (batch[mid] < gid) lo = mid + 1; else hi = mid; }
  int s = lo;
  lo = 0; hi = M;
  while (lo < hi) { int mid = (lo + hi) >> 1; if (batch[mid] < gid + 1) lo = mid + 1; else hi = mid; }
  int e = lo;
  int t = threadIdx.x;
  int cp = t & 63, rs_ = t >> 6;  // col-pair, row phase
  float ax = 0.f, ay = 0.f;
  for (int r = s + rs_; r < e; r += 4) {
    unsigned int v = H[(size_t)r * 64 + cp];
    ax += lo16(v);
    ay += hi16(v);
  }
  __shared__ float redx[256], redy[256];
  __shared__ float g[128];
  redx[t] = ax;
  redy[t] = ay;
  __syncthreads();
  if (t < 128) {
    int cpp = t >> 1;
    float sum;
    if (t & 1)
      sum = redy[cpp] + redy[64 + cpp] + redy[128 + cpp] + redy[192 + cpp];
    else
      sum = redx[cpp] + redx[64 + cpp] + redx[128 + cpp] + redx[192 + cpp];
    g[t] = sum * scale[t] + (float)(e - s) * shift[t];
  }
  __syncthreads();
  if (t < 128) {
    float a2 = bp[t];
#pragma unroll 8
    for (int k = 0; k < 128; ++k) a2 = fmaf(g[k], Wp[k * 128 + t], a2);
    out[gid * 128 + t] = fmaxf(a2, 0.f);
  }
}

extern "C" void kernel_launch(void* const* d_in, const int* in_sizes, int n_in,
                              void* d_out, int out_size, void* d_ws, size_t ws_size,
                              hipStream_t stream) {
  const float* x = (const float*)d_in[0];
  const int* ei = (const int*)d_in[1];
  const int* batch = (const int*)d_in[2];
  const float* W1 = (const float*)d_in[3];
  const float* b1 = (const float*)d_in[4];
  const float* W2 = (const float*)d_in[5];
  const float* b2 = (const float*)d_in[6];
  const float* gamma = (const float*)d_in[7];
  const float* beta = (const float*)d_in[8];
  const float* Wp = (const float*)d_in[9];
  const float* bp = (const float*)d_in[10];
  float* out = (float*)d_out;

  int M = in_sizes[0] / 128;
  int E = in_sizes[1] / 2;
  int L = in_sizes[3] / (128 * 128);
  int G = out_size / 128;
  const int* srcp = ei;
  const int* dstp = ei + E;

  char* w = (char*)d_ws;
  auto alloc = [&](size_t bytes) {
    char* p = w;
    w += (bytes + 255) & ~(size_t)255;
    return p;
  };
  int nblk = (M + 63) / 64;
  unsigned int* bufA = (unsigned int*)alloc((size_t)M * 64 * 4);
  unsigned int* bufB = (unsigned int*)alloc((size_t)M * 64 * 4);
  unsigned short* WT = (unsigned short*)alloc((size_t)L * 2 * 16384 * 2);
  int* counts = (int*)alloc((size_t)M * 4);
  int* incl = (int*)alloc((size_t)M * 4);
  int* bsums = (int*)alloc(128 * 4);
  int* offsets = (int*)alloc((size_t)(M + 1) * 4);
  int* cursor = (int*)alloc((size_t)M * 4);
  int* srcs = (int*)alloc((size_t)E * 4);
  float* pstat = (float*)alloc((size_t)nblk * 256 * 4);
  float* stats = (float*)alloc(2 * 128 * 4);
  float* scale = stats;
  float* shift = stats + 128;

  int nb = (M + 511) / 512;

  prep_kernel<<<2048, 256, 0, stream>>>(x, bufA, counts, scale, shift, M);
  hist_kernel<<<(E + 255) / 256, 256, 0, stream>>>(dstp, counts, E);
  scan1_kernel<<<nb, 512, 0, stream>>>(counts, incl, bsums, M);
  scan2_kernel<<<1, 128, 0, stream>>>(bsums, nb);
  scan3_kernel<<<(M + 255) / 256, 256, 0, stream>>>(counts, incl, bsums, offsets, cursor, M);
  fill_kernel<<<(E + 255) / 256, 256, 0, stream>>>(srcp, dstp, cursor, srcs, E);
  prep_w_kernel<<<(L * 2 * 16384 + 255) / 256, 256, 0, stream>>>(W1, W2, WT, L * 2 * 16384);

  float invM = 1.0f / (float)M;
  unsigned int* cur = bufA;
  unsigned int* nxt = bufB;
  for (int l = 0; l < L; ++l) {
    layer_kernel<<<nblk, 512, 0, stream>>>(
        cur, offsets, srcs, scale, shift, WT + (size_t)(2 * l) * 16384, b1 + l * 128,
        WT + (size_t)(2 * l + 1) * 16384, b2 + l * 128, (unsigned short*)nxt, pstat, M);
    bn_stats_kernel<<<128, 256, 0, stream>>>(pstat, nblk, gamma + l * 128, beta + l * 128,
                                             scale, shift, invM);
    unsigned int* tmp = cur; cur = nxt; nxt = tmp;
  }

  pool_proj_kernel<<<G, 256, 0, stream>>>(cur, batch, scale, shift, Wp, bp, out, M);
}